// Round 11
// baseline (220.788 us; speedup 1.0000x reference)
//
#include <hip/hip_runtime.h>
#include <hip/hip_bf16.h>

typedef __hip_bfloat16 bf16;
typedef unsigned short u16;
typedef unsigned int u32;
typedef float f32x4 __attribute__((ext_vector_type(4)));
typedef float f32x16 __attribute__((ext_vector_type(16)));
typedef __bf16 bf16x8 __attribute__((ext_vector_type(8)));
typedef u16 u16x8 __attribute__((ext_vector_type(8)));

#define DMODEL 1024
#define NH 16
#define HD 64
#define QKV_LD 3072

typedef __attribute__((address_space(1))) const void* as1_cvp;
typedef __attribute__((address_space(3))) void* as3_vp;

__device__ __forceinline__ void gload_lds16(const void* g, void* l) {
  __builtin_amdgcn_global_load_lds((as1_cvp)g, (as3_vp)l, 16, 0, 0);
}

__device__ __forceinline__ f32x4 mfma16(bf16x8 a, bf16x8 b, f32x4 c) {
  return __builtin_amdgcn_mfma_f32_16x16x32_bf16(a, b, c, 0, 0, 0);
}
__device__ __forceinline__ f32x16 mfma32(bf16x8 a, bf16x8 b, f32x16 c) {
  return __builtin_amdgcn_mfma_f32_32x32x16_bf16(a, b, c, 0, 0, 0);
}

__device__ __forceinline__ u16 f2b(float f) {
  union { bf16 b; u16 s; } u; u.b = __float2bfloat16(f); return u.s;
}
__device__ __forceinline__ u32 pkbf(float a, float b) {
  union { __hip_bfloat162 h; u32 u; } cv;
  cv.h = __float22bfloat162_rn(make_float2(a, b));
  return cv.u;
}

// ---------------- fp32 -> bf16 conversion, 4 elems/thread ----------------
__global__ __launch_bounds__(256) void cvt_kernel(const float* __restrict__ src,
                                                  bf16* __restrict__ dst, int n) {
  int i = (blockIdx.x * 256 + threadIdx.x) * 4;
  if (i >= n) return;
  float4 v = *(const float4*)(src + i);
  union { ushort4 u; bf16 h[4]; } o;
  o.h[0] = __float2bfloat16(v.x);
  o.h[1] = __float2bfloat16(v.y);
  o.h[2] = __float2bfloat16(v.z);
  o.h[3] = __float2bfloat16(v.w);
  *(ushort4*)(dst + i) = o.u;
}

// ---------------- RoPE on Q and K regions of QKV, in place ----------------
// Q additionally scaled by 0.125*log2(e): scores come out in log2 domain,
// so softmax uses raw v_exp_f32 (exp2) with no per-element multiply.
__global__ __launch_bounds__(256) void rope_kernel(bf16* __restrict__ qkv) {
  int idx = blockIdx.x * 256 + threadIdx.x;
  int p = idx & 511;
  int s = (idx >> 9) & 4095;
  int region = idx >> 21;
  int i = p & 31;
  int h = p >> 5;
  long base = (long)s * QKV_LD + region * DMODEL + h * HD + 2 * i;
  float x1 = __bfloat162float(qkv[base]);
  float x2 = __bfloat162float(qkv[base + 1]);
  float invf = powf(10000.0f, -(float)(2 * i) / 64.0f);
  float ang = (float)s * invf;
  float sn, cs;
  sincosf(ang, &sn, &cs);
  float scale = (region == 0) ? 0.18033688011112042f : 1.0f;  // 0.125*log2(e)
  float r1 = (x1 * cs - x2 * sn) * scale;
  float r2 = (x1 * sn + x2 * cs) * scale;
  qkv[base]     = __float2bfloat16(r1);
  qkv[base + 1] = __float2bfloat16(r2);
}

// ---------------- NT GEMM (unchanged) ----------------
template <int OUT_BF16>
__global__ __launch_bounds__(256) void gemm_bt(const bf16* __restrict__ A,
                                               const bf16* __restrict__ B,
                                               void* __restrict__ Cout,
                                               const float* __restrict__ bias,
                                               int M, int N, int K) {
  __shared__ __align__(16) bf16 As[128 * 32];
  __shared__ __align__(16) bf16 Bs[128 * 32];
  const int tid = threadIdx.x;
  const int lane = tid & 63;
  const int wid = tid >> 6;
  const int brow = blockIdx.y * 128;
  const int bcol = blockIdx.x * 128;
  const int wr = wid >> 1, wc = wid & 1;

  f32x4 acc[4][4] = {};

  const int srow = lane >> 2;
  const int scol = (lane & 3) * 8;
  const bf16* Ag = A + (long)(brow + wid * 32 + srow) * K + scol;
  const bf16* Bg = B + (long)(bcol + wid * 32 + srow) * K + scol;
  bf16* AsW = As + wid * 32 * 32;
  bf16* BsW = Bs + wid * 32 * 32;
  const int kof = (lane >> 4) * 8;
  const int r16 = lane & 15;

  for (int k0 = 0; k0 < K; k0 += 32) {
    __syncthreads();
    gload_lds16(Ag + k0, AsW);
    gload_lds16(Ag + k0 + (long)16 * K, AsW + 16 * 32);
    gload_lds16(Bg + k0, BsW);
    gload_lds16(Bg + k0 + (long)16 * K, BsW + 16 * 32);
    __syncthreads();
    bf16x8 af[4], bfr[4];
#pragma unroll
    for (int m = 0; m < 4; ++m)
      af[m] = *(const bf16x8*)(As + (wr * 64 + m * 16 + r16) * 32 + kof);
#pragma unroll
    for (int n = 0; n < 4; ++n)
      bfr[n] = *(const bf16x8*)(Bs + (wc * 64 + n * 16 + r16) * 32 + kof);
#pragma unroll
    for (int m = 0; m < 4; ++m)
#pragma unroll
      for (int n = 0; n < 4; ++n)
        acc[m][n] = mfma16(af[m], bfr[n], acc[m][n]);
  }

  const int r0 = (lane >> 4) * 4;
#pragma unroll
  for (int m = 0; m < 4; ++m) {
#pragma unroll
    for (int n = 0; n < 4; ++n) {
      int row = brow + wr * 64 + m * 16 + r0;
      int col = bcol + wc * 64 + n * 16 + r16;
#pragma unroll
      for (int r = 0; r < 4; ++r) {
        if (OUT_BF16) {
          ((bf16*)Cout)[(long)(row + r) * N + col] = __float2bfloat16(acc[m][n][r]);
        } else {
          ((float*)Cout)[(long)(row + r) * N + col] = acc[m][n][r] + bias[col];
        }
      }
    }
  }
}

// ---------------- causal flash attention (v9b: paired-sub joint softmax) ----
// v8 + (a) sub-blocks processed in PAIRS (64 kv) through ONE joint online-
// softmax update: batched QK (8 MFMA, ILP2), joint max, single shfl, single
// defer/rescale, exp2 against joint m, batched PV (8 MFMA);
// (b) l-sum kept as own-lane PARTIAL, combined once in the epilogue;
// (c) exp in log2 domain (Q pre-scaled by 0.125*log2e in rope) -> exp2f
// (lowers to v_exp_f32), defer threshold 11.0 (log2 units).
__global__ __launch_bounds__(256, 2) void attn_kernel(const bf16* __restrict__ qkv,
                                                      bf16* __restrict__ ctx) {
  __shared__ __align__(16) bf16 smem[32768];   // 64 KB
  bf16 (*Ks)[128][64] = (bf16(*)[128][64])(smem);           // 2 bufs, [kv][d]
  bf16 (*Vt)[64][128] = (bf16(*)[64][128])(smem + 16384);   // 2 bufs, [d][kv]

  const int tid = threadIdx.x;
  const int lane = tid & 63;
  const int wid = tid >> 6;            // 0..3
  const int hi = lane >> 5;
  const int l31 = lane & 31;
  const int bq = blockIdx.x >> 4;      // 0..31
  const int tier = (blockIdx.x < 256) ? bq : (47 - bq);   // balanced pairing
  const int h = blockIdx.x & 15;
  const int grp = wid >> 1;
  const int wslot = wid & 1;
  const int hv = (tier >> 4) & 1;      // which group is heavy
  const int qblk = (grp == hv) ? (63 - tier) : tier;   // 64-row q tile
  const int q0w = qblk * 64 + wslot * 32;              // wave's q base
  const long kcol = DMODEL + (long)h * HD;
  const long vcol = 2 * DMODEL + (long)h * HD;
  const u16* qkv16 = (const u16*)qkv;

  // Q B-fragments: lane holds Q[q=l31][d = kt*16 + hi*8 .. +8]
  bf16x8 qf[4];
  {
    const bf16* qp = qkv + (long)(q0w + l31) * QKV_LD + h * HD + hi * 8;
#pragma unroll
    for (int kt = 0; kt < 4; ++kt) qf[kt] = *(const bf16x8*)(qp + kt * 16);
  }

  const int kOff = ((lane & 7) ^ (lane >> 3)) * 8;   // pre-swizzled K src col
  const int lr = lane >> 3;                          // dest row within 8-chunk
  const int srowp = (lr & 3) + 8 * (lr >> 2);        // sigma base for this lane

  // hoisted swizzled LDS element offsets (sub/cur-invariant parts)
  int kro[4];
#pragma unroll
  for (int kt = 0; kt < 4; ++kt)
    kro[kt] = l31 * 64 + ((((kt << 1) | hi) ^ (l31 & 7)) * 8);
  const int vbase = l31 * 128;
  const int vslotx = l31 & 15;

  f32x16 acc[2] = {};
  float m_r = -1e30f, l_r = 0.0f;      // l_r = OWN-LANE partial sum

  const int nkb = (65 - tier) >> 1;    // KV blocks of 128 (covers heavy tile)
  u16x8 va, vb, vc, vd;

  // prologue: stage KV block 0 into buf 0 (wave wid stages sub wid, sigma rows)
  {
#pragma unroll
    for (int c = 0; c < 4; ++c)
      gload_lds16(qkv + (long)(wid * 32 + srowp + 4 * (c & 1) + 16 * (c >> 1)) * QKV_LD + kcol + kOff,
                  &Ks[0][wid * 32 + c * 8][0]);
    const u16* vp = qkv16 + (long)(wid * 32) * QKV_LD + vcol + lane;
#pragma unroll
    for (int j = 0; j < 8; ++j) va[j] = vp[(long)j * QKV_LD];
#pragma unroll
    for (int j = 0; j < 8; ++j) vb[j] = vp[(long)(8 + j) * QKV_LD];
#pragma unroll
    for (int j = 0; j < 8; ++j) vc[j] = vp[(long)(16 + j) * QKV_LD];
#pragma unroll
    for (int j = 0; j < 8; ++j) vd[j] = vp[(long)(24 + j) * QKV_LD];
    *(u16x8*)(&Vt[0][lane][((wid * 4 + 0) ^ (lane & 15)) * 8]) = va;
    *(u16x8*)(&Vt[0][lane][((wid * 4 + 1) ^ (lane & 15)) * 8]) = vb;
    *(u16x8*)(&Vt[0][lane][((wid * 4 + 2) ^ (lane & 15)) * 8]) = vc;
    *(u16x8*)(&Vt[0][lane][((wid * 4 + 3) ^ (lane & 15)) * 8]) = vd;
  }

  for (int kb = 0; kb < nkb; ++kb) {
    const int cur = kb & 1;
    const int kv0 = kb * 128;
    const bool pre = (kb + 1 < nkb);
    __syncthreads();   // staging of block kb visible; prev iter reads done

    // prefetch next KV block: K -> LDS (other buf, sigma rows), V -> regs
    if (pre) {
      const long kvn = kv0 + 128;
#pragma unroll
      for (int c = 0; c < 4; ++c)
        gload_lds16(qkv + (kvn + wid * 32 + srowp + 4 * (c & 1) + 16 * (c >> 1)) * QKV_LD + kcol + kOff,
                    &Ks[cur ^ 1][wid * 32 + c * 8][0]);
      const u16* vp = qkv16 + (kvn + wid * 32) * QKV_LD + vcol + lane;
#pragma unroll
      for (int j = 0; j < 8; ++j) va[j] = vp[(long)j * QKV_LD];
#pragma unroll
      for (int j = 0; j < 8; ++j) vb[j] = vp[(long)(8 + j) * QKV_LD];
#pragma unroll
      for (int j = 0; j < 8; ++j) vc[j] = vp[(long)(16 + j) * QKV_LD];
#pragma unroll
      for (int j = 0; j < 8; ++j) vd[j] = vp[(long)(24 + j) * QKV_LD];
    }

    const bf16* KsC = &Ks[cur][0][0];
    const bf16* VtC = &Vt[cur][0][0];

    // two sub-PAIRS of 64 kv each, one joint online-softmax update per pair
#pragma unroll
    for (int pr = 0; pr < 2; ++pr) {
      const int s0 = pr * 2;
      const int kvs0 = kv0 + s0 * 32;
      if (kvs0 > q0w + 31) continue;       // pair fully masked (wave-uniform)
      const int kvs1 = kvs0 + 32;
      const bool two = (kvs1 <= q0w + 31);

      // batched S^T = K * Q^T for both subs
      f32x16 ca = {}, cb = {};
      __builtin_amdgcn_s_setprio(1);
#pragma unroll
      for (int kt = 0; kt < 4; ++kt) {
        bf16x8 kf = *(const bf16x8*)(KsC + s0 * 2048 + kro[kt]);
        ca = mfma32(kf, qf[kt], ca);
      }
      if (two) {
#pragma unroll
        for (int kt = 0; kt < 4; ++kt) {
          bf16x8 kf = *(const bf16x8*)(KsC + (s0 + 1) * 2048 + kro[kt]);
          cb = mfma32(kf, qf[kt], cb);
        }
      }
      __builtin_amdgcn_s_setprio(0);

      // causal mask; kv of reg r under sigma:
      // kv = kvs + (r&3) + 4*((r>>2)&1) + 8*hi + 16*(r>>3)
      const int q = q0w + l31;
      if (kvs0 + 31 > q0w) {
        const int kvb = kvs0 + 8 * hi;
#pragma unroll
        for (int r = 0; r < 16; ++r) {
          int kv = kvb + (r & 3) + 4 * ((r >> 2) & 1) + 16 * (r >> 3);
          if (kv > q) ca[r] = -1e30f;
        }
      }
      if (two && kvs1 + 31 > q0w) {
        const int kvb = kvs1 + 8 * hi;
#pragma unroll
        for (int r = 0; r < 16; ++r) {
          int kv = kvb + (r & 3) + 4 * ((r >> 2) & 1) + 16 * (r >> 3);
          if (kv > q) cb[r] = -1e30f;
        }
      }

      // joint max over the pair (ILP-2 trees), one cross-lane exchange
      float xa0 = fmaxf(fmaxf(ca[0], ca[1]), fmaxf(ca[2], ca[3]));
      float xa1 = fmaxf(fmaxf(ca[4], ca[5]), fmaxf(ca[6], ca[7]));
      float xa2 = fmaxf(fmaxf(ca[8], ca[9]), fmaxf(ca[10], ca[11]));
      float xa3 = fmaxf(fmaxf(ca[12], ca[13]), fmaxf(ca[14], ca[15]));
      float pmax = fmaxf(fmaxf(xa0, xa1), fmaxf(xa2, xa3));
      if (two) {
        float xb0 = fmaxf(fmaxf(cb[0], cb[1]), fmaxf(cb[2], cb[3]));
        float xb1 = fmaxf(fmaxf(cb[4], cb[5]), fmaxf(cb[6], cb[7]));
        float xb2 = fmaxf(fmaxf(cb[8], cb[9]), fmaxf(cb[10], cb[11]));
        float xb3 = fmaxf(fmaxf(cb[12], cb[13]), fmaxf(cb[14], cb[15]));
        pmax = fmaxf(pmax, fmaxf(fmaxf(xb0, xb1), fmaxf(xb2, xb3)));
      }
      pmax = fmaxf(pmax, __shfl_xor(pmax, 32, 64));

      if (!__all(pmax <= m_r + 11.0f)) {   // defer-max (log2 units)
        float mn = fmaxf(m_r, pmax);
        float al = exp2f(m_r - mn);
        m_r = mn;
        l_r *= al;
#pragma unroll
        for (int dt = 0; dt < 2; ++dt)
#pragma unroll
          for (int r = 0; r < 16; ++r) acc[dt][r] *= al;
      }

      // p = exp2(c - m); own-lane partial sum only (combined in epilogue)
      float pa[16], pb[16];
#pragma unroll
      for (int r = 0; r < 16; ++r) pa[r] = exp2f(ca[r] - m_r);
      float rs = ((pa[0] + pa[1]) + (pa[2] + pa[3])) + ((pa[4] + pa[5]) + (pa[6] + pa[7])) +
                 (((pa[8] + pa[9]) + (pa[10] + pa[11])) + ((pa[12] + pa[13]) + (pa[14] + pa[15])));
      if (two) {
#pragma unroll
        for (int r = 0; r < 16; ++r) pb[r] = exp2f(cb[r] - m_r);
        rs += ((pb[0] + pb[1]) + (pb[2] + pb[3])) + ((pb[4] + pb[5]) + (pb[6] + pb[7])) +
              (((pb[8] + pb[9]) + (pb[10] + pb[11])) + ((pb[12] + pb[13]) + (pb[14] + pb[15])));
      }
      l_r += rs;

      // P^T -> B-fragments: straight in-order pairwise packs (sigma layout)
      union BP { u32 u[4]; bf16x8 v; } f0a, f1a, f0b, f1b;
      f0a.u[0] = pkbf(pa[0], pa[1]);   f0a.u[1] = pkbf(pa[2], pa[3]);
      f0a.u[2] = pkbf(pa[4], pa[5]);   f0a.u[3] = pkbf(pa[6], pa[7]);
      f1a.u[0] = pkbf(pa[8], pa[9]);   f1a.u[1] = pkbf(pa[10], pa[11]);
      f1a.u[2] = pkbf(pa[12], pa[13]); f1a.u[3] = pkbf(pa[14], pa[15]);
      if (two) {
        f0b.u[0] = pkbf(pb[0], pb[1]);   f0b.u[1] = pkbf(pb[2], pb[3]);
        f0b.u[2] = pkbf(pb[4], pb[5]);   f0b.u[3] = pkbf(pb[6], pb[7]);
        f1b.u[0] = pkbf(pb[8], pb[9]);   f1b.u[1] = pkbf(pb[10], pb[11]);
        f1b.u[2] = pkbf(pb[12], pb[13]); f1b.u[3] = pkbf(pb[14], pb[15]);
      }

      // batched O^T += V^T * P^T for the pair
      __builtin_amdgcn_s_setprio(1);
#pragma unroll
      for (int dt = 0; dt < 2; ++dt) {
        const bf16* vrow = VtC + dt * 4096 + vbase;
        bf16x8 v0 = *(const bf16x8*)(vrow + (((s0 * 4 + hi) ^ vslotx) * 8));
        acc[dt] = mfma32(v0, f0a.v, acc[dt]);
        bf16x8 v1 = *(const bf16x8*)(vrow + (((s0 * 4 + 2 + hi) ^ vslotx) * 8));
        acc[dt] = mfma32(v1, f1a.v, acc[dt]);
        if (two) {
          bf16x8 v2 = *(const bf16x8*)(vrow + ((((s0 + 1) * 4 + hi) ^ vslotx) * 8));
          acc[dt] = mfma32(v2, f0b.v, acc[dt]);
          bf16x8 v3 = *(const bf16x8*)(vrow + ((((s0 + 1) * 4 + 2 + hi) ^ vslotx) * 8));
          acc[dt] = mfma32(v3, f1b.v, acc[dt]);
        }
      }
      __builtin_amdgcn_s_setprio(0);
    }

    // write staged V regs into the other buffer
    if (pre) {
      const int nb = cur ^ 1;
      *(u16x8*)(&Vt[nb][lane][((wid * 4 + 0) ^ (lane & 15)) * 8]) = va;
      *(u16x8*)(&Vt[nb][lane][((wid * 4 + 1) ^ (lane & 15)) * 8]) = vb;
      *(u16x8*)(&Vt[nb][lane][((wid * 4 + 2) ^ (lane & 15)) * 8]) = vc;
      *(u16x8*)(&Vt[nb][lane][((wid * 4 + 3) ^ (lane & 15)) * 8]) = vd;
    }
  }

  __syncthreads();   // all waves done with Ks/Vt; LDS reused for epilogue

  // epilogue: combine l partials across the lane pair, then O^T -> LDS -> ctx
  const float l_tot = l_r + __shfl_xor(l_r, 32, 64);
  bf16* scr = smem + wid * 2176;
  const float inv = 1.0f / l_tot;
#pragma unroll
  for (int dt = 0; dt < 2; ++dt)
#pragma unroll
    for (int g2 = 0; g2 < 4; ++g2) {
      union { u16 hh[4]; unsigned long long q8; } pk4;
#pragma unroll
      for (int j = 0; j < 4; ++j) pk4.hh[j] = f2b(acc[dt][g2 * 4 + j] * inv);
      *(unsigned long long*)(scr + l31 * 68 + dt * 32 + g2 * 8 + 4 * hi) = pk4.q8;
    }
  __syncthreads();   // writes ordered & visible before cross-lane reads

  const int qe = lane >> 1, he = lane & 1;
  u16* cp = (u16*)ctx + (long)(q0w + qe) * DMODEL + h * HD + he * 32;
#pragma unroll
  for (int j = 0; j < 4; ++j) {
    u16x8 v = *(const u16x8*)(scr + qe * 68 + he * 32 + j * 8);
    *(u16x8*)(cp + j * 8) = v;
  }
}

extern "C" void kernel_launch(void* const* d_in, const int* in_sizes, int n_in,
                              void* d_out, int out_size, void* d_ws, size_t ws_size,
                              hipStream_t stream) {
  (void)in_sizes; (void)n_in; (void)out_size; (void)ws_size;
  const float* x  = (const float*)d_in[0];
  const float* Wq = (const float*)d_in[1];
  const float* Wk = (const float*)d_in[2];
  const float* Wv = (const float*)d_in[3];
  const float* Wo = (const float*)d_in[4];
  const float* bo = (const float*)d_in[5];
  float* out = (float*)d_out;

  char* ws = (char*)d_ws;
  bf16* xb   = (bf16*)(ws);                   //  8 MB: x in bf16 [4096,1024]
  bf16* wqkv = (bf16*)(ws + 8388608);         //  6 MB: packed Wq;Wk;Wv [3072,1024]
  bf16* wob  = (bf16*)(ws + 14680064);        //  2 MB: Wo [1024,1024]
  bf16* qkvb = (bf16*)(ws + 16777216);        // 24 MB: QKV [4096,3072]
  bf16* ctxb = (bf16*)(ws + 41943040);        //  8 MB: ctx [4096,1024]

  cvt_kernel<<<dim3(4096), dim3(256), 0, stream>>>(x, xb, 4194304);
  cvt_kernel<<<dim3(1024), dim3(256), 0, stream>>>(Wq, wqkv, 1048576);
  cvt_kernel<<<dim3(1024), dim3(256), 0, stream>>>(Wk, wqkv + 1048576, 1048576);
  cvt_kernel<<<dim3(1024), dim3(256), 0, stream>>>(Wv, wqkv + 2097152, 1048576);
  cvt_kernel<<<dim3(1024), dim3(256), 0, stream>>>(Wo, wob, 1048576);

  gemm_bt<1><<<dim3(24, 32), dim3(256), 0, stream>>>(xb, wqkv, (void*)qkvb, nullptr,
                                                     4096, 3072, 1024);
  rope_kernel<<<dim3(16384), dim3(256), 0, stream>>>(qkvb);
  attn_kernel<<<dim3(512), dim3(256), 0, stream>>>(qkvb, ctxb);
  gemm_bt<0><<<dim3(8, 32), dim3(256), 0, stream>>>(ctxb, wob, (void*)out, bo,
                                                    4096, 1024, 1024);
}

// Round 12
// 199.764 us; speedup vs baseline: 1.1052x; 1.1052x over previous
//
#include <hip/hip_runtime.h>
#include <hip/hip_bf16.h>

typedef __hip_bfloat16 bf16;
typedef unsigned short u16;
typedef unsigned int u32;
typedef float f32x4 __attribute__((ext_vector_type(4)));
typedef float f32x16 __attribute__((ext_vector_type(16)));
typedef __bf16 bf16x8 __attribute__((ext_vector_type(8)));
typedef u16 u16x8 __attribute__((ext_vector_type(8)));

#define DMODEL 1024
#define NH 16
#define HD 64
#define QKV_LD 3072

typedef __attribute__((address_space(1))) const void* as1_cvp;
typedef __attribute__((address_space(3))) void* as3_vp;

__device__ __forceinline__ void gload_lds16(const void* g, void* l) {
  __builtin_amdgcn_global_load_lds((as1_cvp)g, (as3_vp)l, 16, 0, 0);
}

__device__ __forceinline__ f32x4 mfma16(bf16x8 a, bf16x8 b, f32x4 c) {
  return __builtin_amdgcn_mfma_f32_16x16x32_bf16(a, b, c, 0, 0, 0);
}
__device__ __forceinline__ f32x16 mfma32(bf16x8 a, bf16x8 b, f32x16 c) {
  return __builtin_amdgcn_mfma_f32_32x32x16_bf16(a, b, c, 0, 0, 0);
}

// raw hardware exp2 (v_exp_f32), no denormal-guard expansion
__device__ __forceinline__ float fexp2(float x) {
#if __has_builtin(__builtin_amdgcn_exp2f)
  return __builtin_amdgcn_exp2f(x);
#else
  return __expf(x * 0.6931471805599453f);
#endif
}

__device__ __forceinline__ u16 f2b(float f) {
  union { bf16 b; u16 s; } u; u.b = __float2bfloat16(f); return u.s;
}
__device__ __forceinline__ u32 pkbf(float a, float b) {
  union { __hip_bfloat162 h; u32 u; } cv;
  cv.h = __float22bfloat162_rn(make_float2(a, b));
  return cv.u;
}

// ---------------- fp32 -> bf16 conversion, 4 elems/thread ----------------
__global__ __launch_bounds__(256) void cvt_kernel(const float* __restrict__ src,
                                                  bf16* __restrict__ dst, int n) {
  int i = (blockIdx.x * 256 + threadIdx.x) * 4;
  if (i >= n) return;
  float4 v = *(const float4*)(src + i);
  union { ushort4 u; bf16 h[4]; } o;
  o.h[0] = __float2bfloat16(v.x);
  o.h[1] = __float2bfloat16(v.y);
  o.h[2] = __float2bfloat16(v.z);
  o.h[3] = __float2bfloat16(v.w);
  *(ushort4*)(dst + i) = o.u;
}

// ---------------- RoPE on Q and K regions of QKV, in place ----------------
// Q additionally scaled by 0.125*log2(e): scores come out in log2 domain,
// so softmax uses raw v_exp_f32 (exp2) with no per-element multiply.
__global__ __launch_bounds__(256) void rope_kernel(bf16* __restrict__ qkv) {
  int idx = blockIdx.x * 256 + threadIdx.x;
  int p = idx & 511;
  int s = (idx >> 9) & 4095;
  int region = idx >> 21;
  int i = p & 31;
  int h = p >> 5;
  long base = (long)s * QKV_LD + region * DMODEL + h * HD + 2 * i;
  float x1 = __bfloat162float(qkv[base]);
  float x2 = __bfloat162float(qkv[base + 1]);
  float invf = powf(10000.0f, -(float)(2 * i) / 64.0f);
  float ang = (float)s * invf;
  float sn, cs;
  sincosf(ang, &sn, &cs);
  float scale = (region == 0) ? 0.18033688011112042f : 1.0f;  // 0.125*log2(e)
  float r1 = (x1 * cs - x2 * sn) * scale;
  float r2 = (x1 * sn + x2 * cs) * scale;
  qkv[base]     = __float2bfloat16(r1);
  qkv[base + 1] = __float2bfloat16(r2);
}

// ---------------- NT GEMM (unchanged) ----------------
template <int OUT_BF16>
__global__ __launch_bounds__(256) void gemm_bt(const bf16* __restrict__ A,
                                               const bf16* __restrict__ B,
                                               void* __restrict__ Cout,
                                               const float* __restrict__ bias,
                                               int M, int N, int K) {
  __shared__ __align__(16) bf16 As[128 * 32];
  __shared__ __align__(16) bf16 Bs[128 * 32];
  const int tid = threadIdx.x;
  const int lane = tid & 63;
  const int wid = tid >> 6;
  const int brow = blockIdx.y * 128;
  const int bcol = blockIdx.x * 128;
  const int wr = wid >> 1, wc = wid & 1;

  f32x4 acc[4][4] = {};

  const int srow = lane >> 2;
  const int scol = (lane & 3) * 8;
  const bf16* Ag = A + (long)(brow + wid * 32 + srow) * K + scol;
  const bf16* Bg = B + (long)(bcol + wid * 32 + srow) * K + scol;
  bf16* AsW = As + wid * 32 * 32;
  bf16* BsW = Bs + wid * 32 * 32;
  const int kof = (lane >> 4) * 8;
  const int r16 = lane & 15;

  for (int k0 = 0; k0 < K; k0 += 32) {
    __syncthreads();
    gload_lds16(Ag + k0, AsW);
    gload_lds16(Ag + k0 + (long)16 * K, AsW + 16 * 32);
    gload_lds16(Bg + k0, BsW);
    gload_lds16(Bg + k0 + (long)16 * K, BsW + 16 * 32);
    __syncthreads();
    bf16x8 af[4], bfr[4];
#pragma unroll
    for (int m = 0; m < 4; ++m)
      af[m] = *(const bf16x8*)(As + (wr * 64 + m * 16 + r16) * 32 + kof);
#pragma unroll
    for (int n = 0; n < 4; ++n)
      bfr[n] = *(const bf16x8*)(Bs + (wc * 64 + n * 16 + r16) * 32 + kof);
#pragma unroll
    for (int m = 0; m < 4; ++m)
#pragma unroll
      for (int n = 0; n < 4; ++n)
        acc[m][n] = mfma16(af[m], bfr[n], acc[m][n]);
  }

  const int r0 = (lane >> 4) * 4;
#pragma unroll
  for (int m = 0; m < 4; ++m) {
#pragma unroll
    for (int n = 0; n < 4; ++n) {
      int row = brow + wr * 64 + m * 16 + r0;
      int col = bcol + wc * 64 + n * 16 + r16;
#pragma unroll
      for (int r = 0; r < 4; ++r) {
        if (OUT_BF16) {
          ((bf16*)Cout)[(long)(row + r) * N + col] = __float2bfloat16(acc[m][n][r]);
        } else {
          ((float*)Cout)[(long)(row + r) * N + col] = acc[m][n][r] + bias[col];
        }
      }
    }
  }
}

// ---------------- causal flash attention (v10: v9b + raw-HW exp2) ----------
// Identical to v9b except exp2f (which LLVM expands to a guarded multi-inst
// sequence without fast-math) is replaced by __builtin_amdgcn_exp2f — the
// bare v_exp_f32. Isolates "exp was slow" from "pairing is bad".
__global__ __launch_bounds__(256, 2) void attn_kernel(const bf16* __restrict__ qkv,
                                                      bf16* __restrict__ ctx) {
  __shared__ __align__(16) bf16 smem[32768];   // 64 KB
  bf16 (*Ks)[128][64] = (bf16(*)[128][64])(smem);           // 2 bufs, [kv][d]
  bf16 (*Vt)[64][128] = (bf16(*)[64][128])(smem + 16384);   // 2 bufs, [d][kv]

  const int tid = threadIdx.x;
  const int lane = tid & 63;
  const int wid = tid >> 6;            // 0..3
  const int hi = lane >> 5;
  const int l31 = lane & 31;
  const int bq = blockIdx.x >> 4;      // 0..31
  const int tier = (blockIdx.x < 256) ? bq : (47 - bq);   // balanced pairing
  const int h = blockIdx.x & 15;
  const int grp = wid >> 1;
  const int wslot = wid & 1;
  const int hv = (tier >> 4) & 1;      // which group is heavy
  const int qblk = (grp == hv) ? (63 - tier) : tier;   // 64-row q tile
  const int q0w = qblk * 64 + wslot * 32;              // wave's q base
  const long kcol = DMODEL + (long)h * HD;
  const long vcol = 2 * DMODEL + (long)h * HD;
  const u16* qkv16 = (const u16*)qkv;

  // Q B-fragments: lane holds Q[q=l31][d = kt*16 + hi*8 .. +8]
  bf16x8 qf[4];
  {
    const bf16* qp = qkv + (long)(q0w + l31) * QKV_LD + h * HD + hi * 8;
#pragma unroll
    for (int kt = 0; kt < 4; ++kt) qf[kt] = *(const bf16x8*)(qp + kt * 16);
  }

  const int kOff = ((lane & 7) ^ (lane >> 3)) * 8;   // pre-swizzled K src col
  const int lr = lane >> 3;                          // dest row within 8-chunk
  const int srowp = (lr & 3) + 8 * (lr >> 2);        // sigma base for this lane

  // hoisted swizzled LDS element offsets (sub/cur-invariant parts)
  int kro[4];
#pragma unroll
  for (int kt = 0; kt < 4; ++kt)
    kro[kt] = l31 * 64 + ((((kt << 1) | hi) ^ (l31 & 7)) * 8);
  const int vbase = l31 * 128;
  const int vslotx = l31 & 15;

  f32x16 acc[2] = {};
  float m_r = -1e30f, l_r = 0.0f;      // l_r = OWN-LANE partial sum

  const int nkb = (65 - tier) >> 1;    // KV blocks of 128 (covers heavy tile)
  u16x8 va, vb, vc, vd;

  // prologue: stage KV block 0 into buf 0 (wave wid stages sub wid, sigma rows)
  {
#pragma unroll
    for (int c = 0; c < 4; ++c)
      gload_lds16(qkv + (long)(wid * 32 + srowp + 4 * (c & 1) + 16 * (c >> 1)) * QKV_LD + kcol + kOff,
                  &Ks[0][wid * 32 + c * 8][0]);
    const u16* vp = qkv16 + (long)(wid * 32) * QKV_LD + vcol + lane;
#pragma unroll
    for (int j = 0; j < 8; ++j) va[j] = vp[(long)j * QKV_LD];
#pragma unroll
    for (int j = 0; j < 8; ++j) vb[j] = vp[(long)(8 + j) * QKV_LD];
#pragma unroll
    for (int j = 0; j < 8; ++j) vc[j] = vp[(long)(16 + j) * QKV_LD];
#pragma unroll
    for (int j = 0; j < 8; ++j) vd[j] = vp[(long)(24 + j) * QKV_LD];
    *(u16x8*)(&Vt[0][lane][((wid * 4 + 0) ^ (lane & 15)) * 8]) = va;
    *(u16x8*)(&Vt[0][lane][((wid * 4 + 1) ^ (lane & 15)) * 8]) = vb;
    *(u16x8*)(&Vt[0][lane][((wid * 4 + 2) ^ (lane & 15)) * 8]) = vc;
    *(u16x8*)(&Vt[0][lane][((wid * 4 + 3) ^ (lane & 15)) * 8]) = vd;
  }

  for (int kb = 0; kb < nkb; ++kb) {
    const int cur = kb & 1;
    const int kv0 = kb * 128;
    const bool pre = (kb + 1 < nkb);
    __syncthreads();   // staging of block kb visible; prev iter reads done

    // prefetch next KV block: K -> LDS (other buf, sigma rows), V -> regs
    if (pre) {
      const long kvn = kv0 + 128;
#pragma unroll
      for (int c = 0; c < 4; ++c)
        gload_lds16(qkv + (kvn + wid * 32 + srowp + 4 * (c & 1) + 16 * (c >> 1)) * QKV_LD + kcol + kOff,
                    &Ks[cur ^ 1][wid * 32 + c * 8][0]);
      const u16* vp = qkv16 + (kvn + wid * 32) * QKV_LD + vcol + lane;
#pragma unroll
      for (int j = 0; j < 8; ++j) va[j] = vp[(long)j * QKV_LD];
#pragma unroll
      for (int j = 0; j < 8; ++j) vb[j] = vp[(long)(8 + j) * QKV_LD];
#pragma unroll
      for (int j = 0; j < 8; ++j) vc[j] = vp[(long)(16 + j) * QKV_LD];
#pragma unroll
      for (int j = 0; j < 8; ++j) vd[j] = vp[(long)(24 + j) * QKV_LD];
    }

    const bf16* KsC = &Ks[cur][0][0];
    const bf16* VtC = &Vt[cur][0][0];

    // two sub-PAIRS of 64 kv each, one joint online-softmax update per pair
#pragma unroll
    for (int pr = 0; pr < 2; ++pr) {
      const int s0 = pr * 2;
      const int kvs0 = kv0 + s0 * 32;
      if (kvs0 > q0w + 31) continue;       // pair fully masked (wave-uniform)
      const int kvs1 = kvs0 + 32;
      const bool two = (kvs1 <= q0w + 31);

      // batched S^T = K * Q^T for both subs
      f32x16 ca = {}, cb = {};
      __builtin_amdgcn_s_setprio(1);
#pragma unroll
      for (int kt = 0; kt < 4; ++kt) {
        bf16x8 kf = *(const bf16x8*)(KsC + s0 * 2048 + kro[kt]);
        ca = mfma32(kf, qf[kt], ca);
      }
      if (two) {
#pragma unroll
        for (int kt = 0; kt < 4; ++kt) {
          bf16x8 kf = *(const bf16x8*)(KsC + (s0 + 1) * 2048 + kro[kt]);
          cb = mfma32(kf, qf[kt], cb);
        }
      }
      __builtin_amdgcn_s_setprio(0);

      // causal mask; kv of reg r under sigma:
      // kv = kvs + (r&3) + 4*((r>>2)&1) + 8*hi + 16*(r>>3)
      const int q = q0w + l31;
      if (kvs0 + 31 > q0w) {
        const int kvb = kvs0 + 8 * hi;
#pragma unroll
        for (int r = 0; r < 16; ++r) {
          int kv = kvb + (r & 3) + 4 * ((r >> 2) & 1) + 16 * (r >> 3);
          if (kv > q) ca[r] = -1e30f;
        }
      }
      if (two && kvs1 + 31 > q0w) {
        const int kvb = kvs1 + 8 * hi;
#pragma unroll
        for (int r = 0; r < 16; ++r) {
          int kv = kvb + (r & 3) + 4 * ((r >> 2) & 1) + 16 * (r >> 3);
          if (kv > q) cb[r] = -1e30f;
        }
      }

      // joint max over the pair (ILP-2 trees), one cross-lane exchange
      float xa0 = fmaxf(fmaxf(ca[0], ca[1]), fmaxf(ca[2], ca[3]));
      float xa1 = fmaxf(fmaxf(ca[4], ca[5]), fmaxf(ca[6], ca[7]));
      float xa2 = fmaxf(fmaxf(ca[8], ca[9]), fmaxf(ca[10], ca[11]));
      float xa3 = fmaxf(fmaxf(ca[12], ca[13]), fmaxf(ca[14], ca[15]));
      float pmax = fmaxf(fmaxf(xa0, xa1), fmaxf(xa2, xa3));
      if (two) {
        float xb0 = fmaxf(fmaxf(cb[0], cb[1]), fmaxf(cb[2], cb[3]));
        float xb1 = fmaxf(fmaxf(cb[4], cb[5]), fmaxf(cb[6], cb[7]));
        float xb2 = fmaxf(fmaxf(cb[8], cb[9]), fmaxf(cb[10], cb[11]));
        float xb3 = fmaxf(fmaxf(cb[12], cb[13]), fmaxf(cb[14], cb[15]));
        pmax = fmaxf(pmax, fmaxf(fmaxf(xb0, xb1), fmaxf(xb2, xb3)));
      }
      pmax = fmaxf(pmax, __shfl_xor(pmax, 32, 64));

      if (!__all(pmax <= m_r + 11.0f)) {   // defer-max (log2 units)
        float mn = fmaxf(m_r, pmax);
        float al = fexp2(m_r - mn);
        m_r = mn;
        l_r *= al;
#pragma unroll
        for (int dt = 0; dt < 2; ++dt)
#pragma unroll
          for (int r = 0; r < 16; ++r) acc[dt][r] *= al;
      }

      // p = exp2(c - m); own-lane partial sum only (combined in epilogue)
      float pa[16], pb[16];
#pragma unroll
      for (int r = 0; r < 16; ++r) pa[r] = fexp2(ca[r] - m_r);
      float rs = ((pa[0] + pa[1]) + (pa[2] + pa[3])) + ((pa[4] + pa[5]) + (pa[6] + pa[7])) +
                 (((pa[8] + pa[9]) + (pa[10] + pa[11])) + ((pa[12] + pa[13]) + (pa[14] + pa[15])));
      if (two) {
#pragma unroll
        for (int r = 0; r < 16; ++r) pb[r] = fexp2(cb[r] - m_r);
        rs += ((pb[0] + pb[1]) + (pb[2] + pb[3])) + ((pb[4] + pb[5]) + (pb[6] + pb[7])) +
              (((pb[8] + pb[9]) + (pb[10] + pb[11])) + ((pb[12] + pb[13]) + (pb[14] + pb[15])));
      }
      l_r += rs;

      // P^T -> B-fragments: straight in-order pairwise packs (sigma layout)
      union BP { u32 u[4]; bf16x8 v; } f0a, f1a, f0b, f1b;
      f0a.u[0] = pkbf(pa[0], pa[1]);   f0a.u[1] = pkbf(pa[2], pa[3]);
      f0a.u[2] = pkbf(pa[4], pa[5]);   f0a.u[3] = pkbf(pa[6], pa[7]);
      f1a.u[0] = pkbf(pa[8], pa[9]);   f1a.u[1] = pkbf(pa[10], pa[11]);
      f1a.u[2] = pkbf(pa[12], pa[13]); f1a.u[3] = pkbf(pa[14], pa[15]);
      if (two) {
        f0b.u[0] = pkbf(pb[0], pb[1]);   f0b.u[1] = pkbf(pb[2], pb[3]);
        f0b.u[2] = pkbf(pb[4], pb[5]);   f0b.u[3] = pkbf(pb[6], pb[7]);
        f1b.u[0] = pkbf(pb[8], pb[9]);   f1b.u[1] = pkbf(pb[10], pb[11]);
        f1b.u[2] = pkbf(pb[12], pb[13]); f1b.u[3] = pkbf(pb[14], pb[15]);
      }

      // batched O^T += V^T * P^T for the pair
      __builtin_amdgcn_s_setprio(1);
#pragma unroll
      for (int dt = 0; dt < 2; ++dt) {
        const bf16* vrow = VtC + dt * 4096 + vbase;
        bf16x8 v0 = *(const bf16x8*)(vrow + (((s0 * 4 + hi) ^ vslotx) * 8));
        acc[dt] = mfma32(v0, f0a.v, acc[dt]);
        bf16x8 v1 = *(const bf16x8*)(vrow + (((s0 * 4 + 2 + hi) ^ vslotx) * 8));
        acc[dt] = mfma32(v1, f1a.v, acc[dt]);
        if (two) {
          bf16x8 v2 = *(const bf16x8*)(vrow + ((((s0 + 1) * 4 + hi) ^ vslotx) * 8));
          acc[dt] = mfma32(v2, f0b.v, acc[dt]);
          bf16x8 v3 = *(const bf16x8*)(vrow + ((((s0 + 1) * 4 + 2 + hi) ^ vslotx) * 8));
          acc[dt] = mfma32(v3, f1b.v, acc[dt]);
        }
      }
      __builtin_amdgcn_s_setprio(0);
    }

    // write staged V regs into the other buffer
    if (pre) {
      const int nb = cur ^ 1;
      *(u16x8*)(&Vt[nb][lane][((wid * 4 + 0) ^ (lane & 15)) * 8]) = va;
      *(u16x8*)(&Vt[nb][lane][((wid * 4 + 1) ^ (lane & 15)) * 8]) = vb;
      *(u16x8*)(&Vt[nb][lane][((wid * 4 + 2) ^ (lane & 15)) * 8]) = vc;
      *(u16x8*)(&Vt[nb][lane][((wid * 4 + 3) ^ (lane & 15)) * 8]) = vd;
    }
  }

  __syncthreads();   // all waves done with Ks/Vt; LDS reused for epilogue

  // epilogue: combine l partials across the lane pair, then O^T -> LDS -> ctx
  const float l_tot = l_r + __shfl_xor(l_r, 32, 64);
  bf16* scr = smem + wid * 2176;
  const float inv = 1.0f / l_tot;
#pragma unroll
  for (int dt = 0; dt < 2; ++dt)
#pragma unroll
    for (int g2 = 0; g2 < 4; ++g2) {
      union { u16 hh[4]; unsigned long long q8; } pk4;
#pragma unroll
      for (int j = 0; j < 4; ++j) pk4.hh[j] = f2b(acc[dt][g2 * 4 + j] * inv);
      *(unsigned long long*)(scr + l31 * 68 + dt * 32 + g2 * 8 + 4 * hi) = pk4.q8;
    }
  __syncthreads();   // writes ordered & visible before cross-lane reads

  const int qe = lane >> 1, he = lane & 1;
  u16* cp = (u16*)ctx + (long)(q0w + qe) * DMODEL + h * HD + he * 32;
#pragma unroll
  for (int j = 0; j < 4; ++j) {
    u16x8 v = *(const u16x8*)(scr + qe * 68 + he * 32 + j * 8);
    *(u16x8*)(cp + j * 8) = v;
  }
}

extern "C" void kernel_launch(void* const* d_in, const int* in_sizes, int n_in,
                              void* d_out, int out_size, void* d_ws, size_t ws_size,
                              hipStream_t stream) {
  (void)in_sizes; (void)n_in; (void)out_size; (void)ws_size;
  const float* x  = (const float*)d_in[0];
  const float* Wq = (const float*)d_in[1];
  const float* Wk = (const float*)d_in[2];
  const float* Wv = (const float*)d_in[3];
  const float* Wo = (const float*)d_in[4];
  const float* bo = (const float*)d_in[5];
  float* out = (float*)d_out;

  char* ws = (char*)d_ws;
  bf16* xb   = (bf16*)(ws);                   //  8 MB: x in bf16 [4096,1024]
  bf16* wqkv = (bf16*)(ws + 8388608);         //  6 MB: packed Wq;Wk;Wv [3072,1024]
  bf16* wob  = (bf16*)(ws + 14680064);        //  2 MB: Wo [1024,1024]
  bf16* qkvb = (bf16*)(ws + 16777216);        // 24 MB: QKV [4096,3072]
  bf16* ctxb = (bf16*)(ws + 41943040);        //  8 MB: ctx [4096,1024]

  cvt_kernel<<<dim3(4096), dim3(256), 0, stream>>>(x, xb, 4194304);
  cvt_kernel<<<dim3(1024), dim3(256), 0, stream>>>(Wq, wqkv, 1048576);
  cvt_kernel<<<dim3(1024), dim3(256), 0, stream>>>(Wk, wqkv + 1048576, 1048576);
  cvt_kernel<<<dim3(1024), dim3(256), 0, stream>>>(Wv, wqkv + 2097152, 1048576);
  cvt_kernel<<<dim3(1024), dim3(256), 0, stream>>>(Wo, wob, 1048576);

  gemm_bt<1><<<dim3(24, 32), dim3(256), 0, stream>>>(xb, wqkv, (void*)qkvb, nullptr,
                                                     4096, 3072, 1024);
  rope_kernel<<<dim3(16384), dim3(256), 0, stream>>>(qkvb);
  attn_kernel<<<dim3(512), dim3(256), 0, stream>>>(qkvb, ctxb);
  gemm_bt<0><<<dim3(8, 32), dim3(256), 0, stream>>>(ctxb, wob, (void*)out, bo,
                                                    4096, 1024, 1024);
}

// Round 13
// 185.013 us; speedup vs baseline: 1.1934x; 1.0797x over previous
//
#include <hip/hip_runtime.h>
#include <hip/hip_bf16.h>

typedef __hip_bfloat16 bf16;
typedef unsigned short u16;
typedef unsigned int u32;
typedef float f32x4 __attribute__((ext_vector_type(4)));
typedef float f32x16 __attribute__((ext_vector_type(16)));
typedef __bf16 bf16x8 __attribute__((ext_vector_type(8)));
typedef u16 u16x8 __attribute__((ext_vector_type(8)));

#define DMODEL 1024
#define NH 16
#define HD 64
#define QKV_LD 3072

typedef __attribute__((address_space(1))) const void* as1_cvp;
typedef __attribute__((address_space(3))) void* as3_vp;

__device__ __forceinline__ void gload_lds16(const void* g, void* l) {
  __builtin_amdgcn_global_load_lds((as1_cvp)g, (as3_vp)l, 16, 0, 0);
}

__device__ __forceinline__ f32x4 mfma16(bf16x8 a, bf16x8 b, f32x4 c) {
  return __builtin_amdgcn_mfma_f32_16x16x32_bf16(a, b, c, 0, 0, 0);
}
__device__ __forceinline__ f32x16 mfma32(bf16x8 a, bf16x8 b, f32x16 c) {
  return __builtin_amdgcn_mfma_f32_32x32x16_bf16(a, b, c, 0, 0, 0);
}

// raw hardware exp2 (v_exp_f32), no denormal-guard expansion
__device__ __forceinline__ float fexp2(float x) {
#if __has_builtin(__builtin_amdgcn_exp2f)
  return __builtin_amdgcn_exp2f(x);
#else
  return __expf(x * 0.6931471805599453f);
#endif
}

__device__ __forceinline__ u16 f2b(float f) {
  union { bf16 b; u16 s; } u; u.b = __float2bfloat16(f); return u.s;
}
__device__ __forceinline__ u32 pkbf(float a, float b) {
  union { __hip_bfloat162 h; u32 u; } cv;
  cv.h = __float22bfloat162_rn(make_float2(a, b));
  return cv.u;
}

// ---------------- fp32 -> bf16 conversion, 4 elems/thread ----------------
__global__ __launch_bounds__(256) void cvt_kernel(const float* __restrict__ src,
                                                  bf16* __restrict__ dst, int n) {
  int i = (blockIdx.x * 256 + threadIdx.x) * 4;
  if (i >= n) return;
  float4 v = *(const float4*)(src + i);
  union { ushort4 u; bf16 h[4]; } o;
  o.h[0] = __float2bfloat16(v.x);
  o.h[1] = __float2bfloat16(v.y);
  o.h[2] = __float2bfloat16(v.z);
  o.h[3] = __float2bfloat16(v.w);
  *(ushort4*)(dst + i) = o.u;
}

// ---------------- RoPE on Q and K regions of QKV, in place ----------------
// Q additionally scaled by 0.125*log2(e): scores come out in log2 domain,
// so softmax uses raw v_exp_f32 (exp2) with no per-element multiply.
__global__ __launch_bounds__(256) void rope_kernel(bf16* __restrict__ qkv) {
  int idx = blockIdx.x * 256 + threadIdx.x;
  int p = idx & 511;
  int s = (idx >> 9) & 4095;
  int region = idx >> 21;
  int i = p & 31;
  int h = p >> 5;
  long base = (long)s * QKV_LD + region * DMODEL + h * HD + 2 * i;
  float x1 = __bfloat162float(qkv[base]);
  float x2 = __bfloat162float(qkv[base + 1]);
  float invf = powf(10000.0f, -(float)(2 * i) / 64.0f);
  float ang = (float)s * invf;
  float sn, cs;
  sincosf(ang, &sn, &cs);
  float scale = (region == 0) ? 0.18033688011112042f : 1.0f;  // 0.125*log2(e)
  float r1 = (x1 * cs - x2 * sn) * scale;
  float r2 = (x1 * sn + x2 * cs) * scale;
  qkv[base]     = __float2bfloat16(r1);
  qkv[base + 1] = __float2bfloat16(r2);
}

// ---------------- NT GEMM (unchanged) ----------------
template <int OUT_BF16>
__global__ __launch_bounds__(256) void gemm_bt(const bf16* __restrict__ A,
                                               const bf16* __restrict__ B,
                                               void* __restrict__ Cout,
                                               const float* __restrict__ bias,
                                               int M, int N, int K) {
  __shared__ __align__(16) bf16 As[128 * 32];
  __shared__ __align__(16) bf16 Bs[128 * 32];
  const int tid = threadIdx.x;
  const int lane = tid & 63;
  const int wid = tid >> 6;
  const int brow = blockIdx.y * 128;
  const int bcol = blockIdx.x * 128;
  const int wr = wid >> 1, wc = wid & 1;

  f32x4 acc[4][4] = {};

  const int srow = lane >> 2;
  const int scol = (lane & 3) * 8;
  const bf16* Ag = A + (long)(brow + wid * 32 + srow) * K + scol;
  const bf16* Bg = B + (long)(bcol + wid * 32 + srow) * K + scol;
  bf16* AsW = As + wid * 32 * 32;
  bf16* BsW = Bs + wid * 32 * 32;
  const int kof = (lane >> 4) * 8;
  const int r16 = lane & 15;

  for (int k0 = 0; k0 < K; k0 += 32) {
    __syncthreads();
    gload_lds16(Ag + k0, AsW);
    gload_lds16(Ag + k0 + (long)16 * K, AsW + 16 * 32);
    gload_lds16(Bg + k0, BsW);
    gload_lds16(Bg + k0 + (long)16 * K, BsW + 16 * 32);
    __syncthreads();
    bf16x8 af[4], bfr[4];
#pragma unroll
    for (int m = 0; m < 4; ++m)
      af[m] = *(const bf16x8*)(As + (wr * 64 + m * 16 + r16) * 32 + kof);
#pragma unroll
    for (int n = 0; n < 4; ++n)
      bfr[n] = *(const bf16x8*)(Bs + (wc * 64 + n * 16 + r16) * 32 + kof);
#pragma unroll
    for (int m = 0; m < 4; ++m)
#pragma unroll
      for (int n = 0; n < 4; ++n)
        acc[m][n] = mfma16(af[m], bfr[n], acc[m][n]);
  }

  const int r0 = (lane >> 4) * 4;
#pragma unroll
  for (int m = 0; m < 4; ++m) {
#pragma unroll
    for (int n = 0; n < 4; ++n) {
      int row = brow + wr * 64 + m * 16 + r0;
      int col = bcol + wc * 64 + n * 16 + r16;
#pragma unroll
      for (int r = 0; r < 4; ++r) {
        if (OUT_BF16) {
          ((bf16*)Cout)[(long)(row + r) * N + col] = __float2bfloat16(acc[m][n][r]);
        } else {
          ((float*)Cout)[(long)(row + r) * N + col] = acc[m][n][r] + bias[col];
        }
      }
    }
  }
}

// ---------------- causal flash attention (v11: split-KV wave pairs) --------
// grid (1024): t = bid>>4 (0..63), head = bid&15. 256 thr = 4 waves, 32 KB
// LDS -> 4 blocks/CU = 16 waves/CU = 4 waves/SIMD (VGPR<=128 via
// launch_bounds(256,4)). Waves 0,1 both own the HEAVY 32-row q tile
// (qblk32 = 127-t) and split each 64-KV block by parity (wave p computes
// sub p); waves 2,3 same for the LIGHT tile (qblk32 = t). Per-wave serial
// chain per iteration is ONE 32x32 sub. Cross-wave (m,l,acc) merge through
// LDS at the epilogue (exact split-K softmax merge; inactive waves
// contribute exp2(-1e30-m)=0).
__global__ __launch_bounds__(256, 4) void attn_kernel(const bf16* __restrict__ qkv,
                                                      bf16* __restrict__ ctx) {
  __shared__ __align__(16) bf16 smem[16384];   // 32 KB
  bf16 (*Ks)[64][64] = (bf16(*)[64][64])(smem);          // 2 bufs, [kv][d]
  bf16 (*Vt)[64][64] = (bf16(*)[64][64])(smem + 8192);   // 2 bufs, [d][kv]

  const int tid = threadIdx.x;
  const int lane = tid & 63;
  const int wid = tid >> 6;            // 0..3
  const int hi = lane >> 5;
  const int l31 = lane & 31;
  const int t = blockIdx.x >> 4;       // 0..63
  const int h = blockIdx.x & 15;
  const int p = wid & 1;               // kv-half parity within the tile pair
  const int qblk = (wid < 2) ? (127 - t) : t;   // 32-row q tile
  const int q0w = qblk * 32;
  const long kcol = DMODEL + (long)h * HD;
  const long vcol = 2 * DMODEL + (long)h * HD;
  const u16* qkv16 = (const u16*)qkv;

  // Q B-fragments: lane holds Q[q=l31][d = kt*16 + hi*8 .. +8]
  bf16x8 qf[4];
  {
    const bf16* qp = qkv + (long)(q0w + l31) * QKV_LD + h * HD + hi * 8;
#pragma unroll
    for (int kt = 0; kt < 4; ++kt) qf[kt] = *(const bf16x8*)(qp + kt * 16);
  }

  const int kOff = ((lane & 7) ^ (lane >> 3)) * 8;   // pre-swizzled K src col
  const int lr = lane >> 3;
  const int srowp = (lr & 3) + 8 * (lr >> 2);        // sigma base for this lane

  // hoisted swizzled LDS element offsets
  int kro[4];
#pragma unroll
  for (int kt = 0; kt < 4; ++kt)
    kro[kt] = l31 * 64 + ((((kt << 1) | hi) ^ (l31 & 7)) * 8);
  const int vbase = l31 * 64;
  const int vslotx = l31 & 7;

  f32x16 acc[2] = {};
  float m_r = -1e30f, l_r = 0.0f;      // l_r = own-lane partial sum

  const int nkb = (129 - t) >> 1;      // 64-row KV blocks covering heavy tile
  u16x8 va, vb;

  // prologue: stage KV block 0 into buf 0 (4 waves cooperate; K sigma rows)
  {
#pragma unroll
    for (int c2 = 0; c2 < 2; ++c2) {
      const int c = wid * 2 + c2;
      const int sub = c >> 2, cc = c & 3;
      gload_lds16(qkv + (long)(sub * 32 + srowp + 4 * (cc & 1) + 16 * (cc >> 1)) * QKV_LD + kcol + kOff,
                  &Ks[0][c * 8][0]);
    }
    const u16* vp = qkv16 + (long)(wid * 16) * QKV_LD + vcol + lane;
#pragma unroll
    for (int j = 0; j < 8; ++j) va[j] = vp[(long)j * QKV_LD];
#pragma unroll
    for (int j = 0; j < 8; ++j) vb[j] = vp[(long)(8 + j) * QKV_LD];
    *(u16x8*)(&Vt[0][lane][((wid * 2 + 0) ^ (lane & 7)) * 8]) = va;
    *(u16x8*)(&Vt[0][lane][((wid * 2 + 1) ^ (lane & 7)) * 8]) = vb;
  }

  for (int kb = 0; kb < nkb; ++kb) {
    const int cur = kb & 1;
    const int kvs = kb * 64 + p * 32;   // this wave's sub
    const bool pre = (kb + 1 < nkb);
    __syncthreads();   // staging of block kb visible; prev iter reads done

    // prefetch next KV block: K -> LDS (other buf, sigma rows), V -> regs
    if (pre) {
      const long kvn = (long)(kb + 1) * 64;
#pragma unroll
      for (int c2 = 0; c2 < 2; ++c2) {
        const int c = wid * 2 + c2;
        const int sub = c >> 2, cc = c & 3;
        gload_lds16(qkv + (kvn + sub * 32 + srowp + 4 * (cc & 1) + 16 * (cc >> 1)) * QKV_LD + kcol + kOff,
                    &Ks[cur ^ 1][c * 8][0]);
      }
      const u16* vp = qkv16 + (kvn + wid * 16) * QKV_LD + vcol + lane;
#pragma unroll
      for (int j = 0; j < 8; ++j) va[j] = vp[(long)j * QKV_LD];
#pragma unroll
      for (int j = 0; j < 8; ++j) vb[j] = vp[(long)(8 + j) * QKV_LD];
    }

    if (kvs <= q0w + 31) {   // wave-uniform activity test
      const bf16* KsC = &Ks[cur][0][0];
      const bf16* VtC = &Vt[cur][0][0];

      // S^T = K * Q^T over d=64 (4 mfma of k=16) on this wave's sub
      f32x16 c16 = {};
      __builtin_amdgcn_s_setprio(1);
#pragma unroll
      for (int kt = 0; kt < 4; ++kt) {
        bf16x8 kf = *(const bf16x8*)(KsC + p * 2048 + kro[kt]);
        c16 = mfma32(kf, qf[kt], c16);
      }
      __builtin_amdgcn_s_setprio(0);

      // causal mask; kv of reg r under sigma:
      // kv = kvs + (r&3) + 4*((r>>2)&1) + 8*hi + 16*(r>>3)
      if (kvs + 31 > q0w) {
        const int q = q0w + l31;
        const int kvb = kvs + 8 * hi;
#pragma unroll
        for (int r = 0; r < 16; ++r) {
          int kv = kvb + (r & 3) + 4 * ((r >> 2) & 1) + 16 * (r >> 3);
          if (kv > q) c16[r] = -1e30f;
        }
      }

      // per-lane online softmax; pair (l, l^32) holds the 32 kv of this sub
      float x0 = fmaxf(fmaxf(c16[0], c16[1]), fmaxf(c16[2], c16[3]));
      float x1 = fmaxf(fmaxf(c16[4], c16[5]), fmaxf(c16[6], c16[7]));
      float x2 = fmaxf(fmaxf(c16[8], c16[9]), fmaxf(c16[10], c16[11]));
      float x3 = fmaxf(fmaxf(c16[12], c16[13]), fmaxf(c16[14], c16[15]));
      float pmax = fmaxf(fmaxf(x0, x1), fmaxf(x2, x3));
      pmax = fmaxf(pmax, __shfl_xor(pmax, 32, 64));

      if (!__all(pmax <= m_r + 11.0f)) {   // defer-max (log2 units)
        float mn = fmaxf(m_r, pmax);
        float al = fexp2(m_r - mn);
        m_r = mn;
        l_r *= al;
#pragma unroll
        for (int dt = 0; dt < 2; ++dt)
#pragma unroll
          for (int r = 0; r < 16; ++r) acc[dt][r] *= al;
      }

      float pa[16];
#pragma unroll
      for (int r = 0; r < 16; ++r) pa[r] = fexp2(c16[r] - m_r);
      float rs = ((pa[0] + pa[1]) + (pa[2] + pa[3])) + ((pa[4] + pa[5]) + (pa[6] + pa[7])) +
                 (((pa[8] + pa[9]) + (pa[10] + pa[11])) + ((pa[12] + pa[13]) + (pa[14] + pa[15])));
      l_r += rs;

      // P^T -> B-fragments: straight in-order pairwise packs (sigma layout)
      union BP { u32 u[4]; bf16x8 v; } f0, f1;
      f0.u[0] = pkbf(pa[0], pa[1]);   f0.u[1] = pkbf(pa[2], pa[3]);
      f0.u[2] = pkbf(pa[4], pa[5]);   f0.u[3] = pkbf(pa[6], pa[7]);
      f1.u[0] = pkbf(pa[8], pa[9]);   f1.u[1] = pkbf(pa[10], pa[11]);
      f1.u[2] = pkbf(pa[12], pa[13]); f1.u[3] = pkbf(pa[14], pa[15]);

      // O^T += V^T * P^T
      __builtin_amdgcn_s_setprio(1);
#pragma unroll
      for (int dt = 0; dt < 2; ++dt) {
        const bf16* vrow = VtC + dt * 2048 + vbase;
        bf16x8 v0 = *(const bf16x8*)(vrow + (((p * 4 + hi) ^ vslotx) * 8));
        acc[dt] = mfma32(v0, f0.v, acc[dt]);
        bf16x8 v1 = *(const bf16x8*)(vrow + (((p * 4 + 2 + hi) ^ vslotx) * 8));
        acc[dt] = mfma32(v1, f1.v, acc[dt]);
      }
      __builtin_amdgcn_s_setprio(0);
    }

    // write staged V regs into the other buffer
    if (pre) {
      const int nb = cur ^ 1;
      *(u16x8*)(&Vt[nb][lane][((wid * 2 + 0) ^ (lane & 7)) * 8]) = va;
      *(u16x8*)(&Vt[nb][lane][((wid * 2 + 1) ^ (lane & 7)) * 8]) = vb;
    }
  }

  // ---- split-KV merge: waves (0,1) and (2,3) combine (m, l, acc) ----
  __syncthreads();   // everyone done with Ks/Vt; LDS reused
  float* fs = (float*)smem;          // 2 x 2176 floats = 17.4 KB merge area
  if (wid & 1) {
    float* mb = fs + (wid >> 1) * 2176 + lane * 34;
#pragma unroll
    for (int dt = 0; dt < 2; ++dt)
#pragma unroll
      for (int r = 0; r < 16; ++r) mb[dt * 16 + r] = acc[dt][r];
    mb[32] = m_r;
    mb[33] = l_r;
  }
  __syncthreads();
  if (!(wid & 1)) {
    const float* mb = fs + (wid >> 1) * 2176 + lane * 34;
    float m1 = mb[32], l1 = mb[33];
    float ms = fmaxf(m_r, m1);
    float e0 = fexp2(m_r - ms), e1 = fexp2(m1 - ms);
    l_r = l_r * e0 + l1 * e1;
#pragma unroll
    for (int dt = 0; dt < 2; ++dt)
#pragma unroll
      for (int r = 0; r < 16; ++r)
        acc[dt][r] = acc[dt][r] * e0 + mb[dt * 16 + r] * e1;

    // O^T regs -> per-tile LDS transpose scratch (beyond the merge area)
    const float l_tot = l_r + __shfl_xor(l_r, 32, 64);
    const float inv = 1.0f / l_tot;
    bf16* scr = smem + 10240 + (wid >> 1) * 2176;   // byte 20480+, area 4.25KB
#pragma unroll
    for (int dt = 0; dt < 2; ++dt)
#pragma unroll
      for (int g2 = 0; g2 < 4; ++g2) {
        union { u16 hh[4]; unsigned long long q8; } pk4;
#pragma unroll
        for (int j = 0; j < 4; ++j) pk4.hh[j] = f2b(acc[dt][g2 * 4 + j] * inv);
        *(unsigned long long*)(scr + l31 * 68 + dt * 32 + g2 * 8 + 4 * hi) = pk4.q8;
      }
  }
  __syncthreads();   // scratch visible for cross-lane reads
  if (!(wid & 1)) {
    const bf16* scr = smem + 10240 + (wid >> 1) * 2176;
    const int qe = lane >> 1, he = lane & 1;
    u16* cp = (u16*)ctx + (long)(q0w + qe) * DMODEL + h * HD + he * 32;
#pragma unroll
    for (int j = 0; j < 4; ++j) {
      u16x8 v = *(const u16x8*)(scr + qe * 68 + he * 32 + j * 8);
      *(u16x8*)(cp + j * 8) = v;
    }
  }
}

extern "C" void kernel_launch(void* const* d_in, const int* in_sizes, int n_in,
                              void* d_out, int out_size, void* d_ws, size_t ws_size,
                              hipStream_t stream) {
  (void)in_sizes; (void)n_in; (void)out_size; (void)ws_size;
  const float* x  = (const float*)d_in[0];
  const float* Wq = (const float*)d_in[1];
  const float* Wk = (const float*)d_in[2];
  const float* Wv = (const float*)d_in[3];
  const float* Wo = (const float*)d_in[4];
  const float* bo = (const float*)d_in[5];
  float* out = (float*)d_out;

  char* ws = (char*)d_ws;
  bf16* xb   = (bf16*)(ws);                   //  8 MB: x in bf16 [4096,1024]
  bf16* wqkv = (bf16*)(ws + 8388608);         //  6 MB: packed Wq;Wk;Wv [3072,1024]
  bf16* wob  = (bf16*)(ws + 14680064);        //  2 MB: Wo [1024,1024]
  bf16* qkvb = (bf16*)(ws + 16777216);        // 24 MB: QKV [4096,3072]
  bf16* ctxb = (bf16*)(ws + 41943040);        //  8 MB: ctx [4096,1024]

  cvt_kernel<<<dim3(4096), dim3(256), 0, stream>>>(x, xb, 4194304);
  cvt_kernel<<<dim3(1024), dim3(256), 0, stream>>>(Wq, wqkv, 1048576);
  cvt_kernel<<<dim3(1024), dim3(256), 0, stream>>>(Wk, wqkv + 1048576, 1048576);
  cvt_kernel<<<dim3(1024), dim3(256), 0, stream>>>(Wv, wqkv + 2097152, 1048576);
  cvt_kernel<<<dim3(1024), dim3(256), 0, stream>>>(Wo, wob, 1048576);

  gemm_bt<1><<<dim3(24, 32), dim3(256), 0, stream>>>(xb, wqkv, (void*)qkvb, nullptr,
                                                     4096, 3072, 1024);
  rope_kernel<<<dim3(16384), dim3(256), 0, stream>>>(qkvb);
  attn_kernel<<<dim3(1024), dim3(256), 0, stream>>>(qkvb, ctxb);
  gemm_bt<0><<<dim3(8, 32), dim3(256), 0, stream>>>(ctxb, wob, (void*)out, bo,
                                                    4096, 1024, 1024);
}